// Round 4
// baseline (103.304 us; speedup 1.0000x reference)
//
#include <hip/hip_runtime.h>

// ResidualBlock2 (AdderNet): two adder-convs + BN + ReLU + residual.
// N=32, C=32, H=W=32, K=3. No multiplies -> no MFMA; pure VALU (2 instr per
// |x-w| contribution). R4: R1's conflict-free row-major x tile (b32 reads,
// stride-1 lanes) + weights via inline-asm s_load_dwordx8 on the scalar pipe
// (packed [ci*9+tap][32co] layout, wave-uniform address) + LDS-transpose
// stats. VALU floor for both convs ~15.4us.

typedef __attribute__((ext_vector_type(8))) float f32x8;

#define QSCALE (2.5f / 127.f)

__device__ __forceinline__ float quant(float w) {
  float v = rintf(w * (1.0f / QSCALE));     // round-half-even = jnp.round
  v = fminf(fmaxf(v, -127.f), 127.f);
  return v * QSCALE;
}

// quantize + pack: WQ[(ci*9+tap)*32 + co] = quant(w[co][ci*9+tap])
__global__ __launch_bounds__(256) void quant_k(const float* __restrict__ w1,
                                               const float* __restrict__ w2,
                                               float* __restrict__ q1,
                                               float* __restrict__ q2) {
  int i = blockIdx.x * 256 + threadIdx.x;
  if (i >= 18432) return;
  const float* w = (i < 9216) ? w1 : w2;
  float* dst = (i < 9216) ? q1 : q2;
  int j = (i < 9216) ? i : i - 9216;
  int co = j / 288;
  int r = j - co * 288;                     // r = ci*9 + tap
  dst[r * 32 + co] = quant(w[j]);
}

// Block = (n, row-pair). 256 thr = 4 waves; wave oct owns co oct*8..+7.
// Lane: w = l&31 (col), hl = l>>5 (row within pair). 8 outputs/thread.
// grid 512 = 32 n x 16 row-pairs; 2 blocks/CU, 8 waves/CU.
template <bool AFFINE>
__global__ __launch_bounds__(256, 2) void conv_k(
    const float* __restrict__ in,       // [32][32][32][32] conv input
    const float* __restrict__ wq,       // packed [288][32] this conv
    const float* __restrict__ ps_prev,  // [512][32] prev partial sums (or null)
    const float* __restrict__ pq_prev,  // [512][32] prev partial sumsq
    const float* __restrict__ wq_prev,  // packed prev weights (for wb)
    const float* __restrict__ gprev,    // prev gamma
    const float* __restrict__ bprev,    // prev beta
    float* __restrict__ outb,           // raw conv out
    float* __restrict__ ps_out,         // [512][32]
    float* __restrict__ pq_out) {       // [512][32]
  __shared__ __align__(16) float xs[32][4][34];  // 17408 B, rows h0-1..h0+2
  __shared__ float sA[32][64], sB[32][64];       // 16 KB stats transpose
  __shared__ float r2a[32][8], r2b[32][8], r2c[32][8];
  __shared__ float abuf[32], bbuf[32];

  const int tid = threadIdx.x;
  const int blk = blockIdx.x;
  const int n = blk >> 4;
  const int h0 = (blk & 15) << 1;

  if (AFFINE) {
    // Redundant per-block BN1 fold (deterministic): a=g/sqrt(var+eps),
    // b = beta + wb - a*mu. Reads transposed [512][32] partials: coalesced.
    const int c = tid & 31, ch = tid >> 5;       // ch 0..7
    float s = 0.f, q = 0.f;
    const float* pp = ps_prev + ch * 64 * 32 + c;
    const float* qq = pq_prev + ch * 64 * 32 + c;
    #pragma unroll 4
    for (int i2 = 0; i2 < 64; ++i2) { s += pp[i2 * 32]; q += qq[i2 * 32]; }
    float wbp = 0.f;
    const float* wp = wq_prev + ch * 36 * 32 + c;
    #pragma unroll 4
    for (int u = 0; u < 36; ++u) wbp += fabsf(wp[u * 32]);
    r2a[c][ch] = s; r2b[c][ch] = q; r2c[c][ch] = wbp;
    __syncthreads();
    if (tid < 32) {
      double S = 0.0, Q = 0.0; float W = 0.f;
      #pragma unroll
      for (int k = 0; k < 8; ++k) {
        S += (double)r2a[tid][k]; Q += (double)r2b[tid][k]; W += r2c[tid][k];
      }
      const double M = 32768.0;
      const double mu = S / M;
      const double var = Q / M - mu * mu;
      const double inv = 1.0 / sqrt(var + 1e-5);
      const double g = (double)gprev[tid];
      abuf[tid] = (float)(g * inv);
      bbuf[tid] = (float)((double)bprev[tid] + (double)(W * (1.f / 288.f)) - g * inv * mu);
    }
    __syncthreads();
  }

  // stage x tile (rows h0-1..h0+2, cols -1..32), zero-padded; affine on conv2
  for (int i = tid; i < 4352; i += 256) {
    int ci = i / 136;
    int rem = i - ci * 136;
    int r = rem / 34, c = rem - r * 34;
    int h = h0 - 1 + r, w = c - 1;
    float v = 0.f;
    if ((unsigned)h < 32u && (unsigned)w < 32u) {
      v = in[((n * 32 + ci) * 32 + h) * 32 + w];
      if (AFFINE) v = fmaxf(fmaf(abuf[ci], v, bbuf[ci]), 0.f);
    }
    xs[ci][r][c] = v;
  }
  __syncthreads();

  const int l = tid & 63;
  const int w = l & 31, hl = l >> 5;
  const int oct = __builtin_amdgcn_readfirstlane(tid >> 6);  // 0..3, uniform
  const float* wbase = wq + oct * 8;

  float acc[8] = {0.f, 0.f, 0.f, 0.f, 0.f, 0.f, 0.f, 0.f};

  for (int ci = 0; ci < 32; ++ci) {
    const float* xr = &xs[ci][hl][w];
    #pragma unroll
    for (int kh = 0; kh < 3; ++kh) {
      f32x8 wa, wb2, wc;
      const float* wp = wbase + (ci * 9 + kh * 3) * 32;  // wave-uniform
      asm("s_load_dwordx8 %0, %3, 0x0\n\t"
          "s_load_dwordx8 %1, %3, 0x80\n\t"
          "s_load_dwordx8 %2, %3, 0x100\n\t"
          "s_waitcnt lgkmcnt(0)"
          : "=s"(wa), "=s"(wb2), "=s"(wc)
          : "s"(wp));
      const float x0 = xr[kh * 34 + 0];
      const float x1 = xr[kh * 34 + 1];
      const float x2 = xr[kh * 34 + 2];
      #pragma unroll
      for (int jj = 0; jj < 8; ++jj) acc[jj] += fabsf(wa[jj] - x0);
      #pragma unroll
      for (int jj = 0; jj < 8; ++jj) acc[jj] += fabsf(wb2[jj] - x1);
      #pragma unroll
      for (int jj = 0; jj < 8; ++jj) acc[jj] += fabsf(wc[jj] - x2);
    }
  }

  // write raw conv out (64 consecutive floats per wave-store: coalesced)
  const int h = h0 + hl;
  #pragma unroll
  for (int jj = 0; jj < 8; ++jj) {
    const int co = oct * 8 + jj;
    const float o = -acc[jj];
    outb[((n * 32 + co) * 32 + h) * 32 + w] = o;
    sA[co][l] = o;
    sB[co][l] = o * o;
  }
  __syncthreads();
  {
    const int co = tid >> 3, k = tid & 7;   // 32 co x 8 chunks
    float s = 0.f, q = 0.f;
    #pragma unroll
    for (int i2 = 0; i2 < 8; ++i2) { s += sA[co][k * 8 + i2]; q += sB[co][k * 8 + i2]; }
    #pragma unroll
    for (int d = 1; d < 8; d <<= 1) { s += __shfl_xor(s, d); q += __shfl_xor(q, d); }
    if (k == 0) { ps_out[blk * 32 + co] = s; pq_out[blk * 32 + co] = q; }
  }
}

// ---- K4: redundant BN2 fold + relu(a2*o2 + b2 + x) ----
__global__ __launch_bounds__(256) void final_k(
    const float* __restrict__ o2, const float* __restrict__ xres,
    const float* __restrict__ ps, const float* __restrict__ pq,
    const float* __restrict__ wq2, const float* __restrict__ g2,
    const float* __restrict__ b2, float* __restrict__ out) {
  __shared__ float r2a[32][8], r2b[32][8], r2c[32][8];
  __shared__ float abuf[32], bbuf[32];
  const int tid = threadIdx.x;
  const int c = tid & 31, ch = tid >> 5;
  float s = 0.f, q = 0.f;
  const float* pp = ps + ch * 64 * 32 + c;
  const float* qq = pq + ch * 64 * 32 + c;
  #pragma unroll 4
  for (int i2 = 0; i2 < 64; ++i2) { s += pp[i2 * 32]; q += qq[i2 * 32]; }
  float wbp = 0.f;
  const float* wp = wq2 + ch * 36 * 32 + c;
  #pragma unroll 4
  for (int u = 0; u < 36; ++u) wbp += fabsf(wp[u * 32]);
  r2a[c][ch] = s; r2b[c][ch] = q; r2c[c][ch] = wbp;
  __syncthreads();
  if (tid < 32) {
    double S = 0.0, Q = 0.0; float W = 0.f;
    #pragma unroll
    for (int k = 0; k < 8; ++k) {
      S += (double)r2a[tid][k]; Q += (double)r2b[tid][k]; W += r2c[tid][k];
    }
    const double M = 32768.0;
    const double mu = S / M;
    const double var = Q / M - mu * mu;
    const double inv = 1.0 / sqrt(var + 1e-5);
    const double g = (double)g2[tid];
    abuf[tid] = (float)(g * inv);
    bbuf[tid] = (float)((double)b2[tid] + (double)(W * (1.f / 288.f)) - g * inv * mu);
  }
  __syncthreads();

  const int base = blockIdx.x * 512;  // float4 units; 512 x 512 = 262144
  for (int i = tid; i < 512; i += 256) {
    const int f4 = base + i;
    const int cc = (f4 >> 8) & 31;
    const float4 o = ((const float4*)o2)[f4];
    const float4 xr = ((const float4*)xres)[f4];
    const float av = abuf[cc], bv = bbuf[cc];
    float4 r;
    r.x = fmaxf(fmaf(av, o.x, bv) + xr.x, 0.f);
    r.y = fmaxf(fmaf(av, o.y, bv) + xr.y, 0.f);
    r.z = fmaxf(fmaf(av, o.z, bv) + xr.z, 0.f);
    r.w = fmaxf(fmaf(av, o.w, bv) + xr.w, 0.f);
    ((float4*)out)[f4] = r;
  }
}

extern "C" void kernel_launch(void* const* d_in, const int* in_sizes, int n_in,
                              void* d_out, int out_size, void* d_ws, size_t ws_size,
                              hipStream_t stream) {
  const float* x   = (const float*)d_in[0];
  const float* w1  = (const float*)d_in[1];
  const float* g1  = (const float*)d_in[2];
  const float* be1 = (const float*)d_in[3];
  const float* w2  = (const float*)d_in[4];
  const float* g2  = (const float*)d_in[5];
  const float* be2 = (const float*)d_in[6];
  float* ws = (float*)d_ws;

  float* WQ1 = ws;                  // 9216  (packed [288][32])
  float* WQ2 = ws + 9216;           // 9216
  float* PS1 = ws + 18432;          // [512][32] = 16384
  float* PQ1 = ws + 34816;          // 16384
  float* PS2 = ws + 51200;          // 16384
  float* PQ2 = ws + 67584;          // 16384
  float* O1  = ws + 83968;          // 1048576 (16B aligned: 335872 B)
  float* O2  = O1 + 1048576;        // 1048576
  float* out = (float*)d_out;

  quant_k<<<72, 256, 0, stream>>>(w1, w2, WQ1, WQ2);
  conv_k<false><<<512, 256, 0, stream>>>(x, WQ1, nullptr, nullptr, nullptr,
                                         nullptr, nullptr, O1, PS1, PQ1);
  conv_k<true><<<512, 256, 0, stream>>>(O1, WQ2, PS1, PQ1, WQ1, g1, be1,
                                        O2, PS2, PQ2);
  final_k<<<512, 256, 0, stream>>>(O2, x, PS2, PQ2, WQ2, g2, be2, out);
}